// Round 1
// baseline (517.758 us; speedup 1.0000x reference)
//
#include <hip/hip_runtime.h>
#include <math.h>

#define NCLASS 32000
#define NROWS  2048
#define TEMP_F 4.0f

// log(32000.0) in double
#define TAU_D 10.373491181781864
#define E_D   2.718281828459045

// Principal-branch Lambert W, mirrors the reference's 8 Halley iterations.
__device__ __forceinline__ double lambertw_d(double y) {
    double ey1 = fmax(E_D * y + 1.0, 0.0);
    double w_small = -1.0 + sqrt(2.0 * ey1);
    double ys = fmax(y, 1.0 + 1e-6);
    double ly = log(ys);
    double w_big = ly - log(fmax(ly, 1e-6));
    double w = (y < 1.0) ? w_small : w_big;
#pragma unroll
    for (int i = 0; i < 8; ++i) {
        double ew = exp(w);
        double f = w * ew - y;
        double wp1 = w + 1.0;
        double safe_wp1 = (fabs(wp1) > 1e-6) ? wp1 : 1e-6;
        double denom = ew * wp1 - (w + 2.0) * f / (2.0 * safe_wp1);
        if (!(fabs(denom) > 1e-12)) denom = 1e-12;
        w = w - f / denom;
    }
    return w;
}

__device__ __forceinline__ void upd(float x, float t,
                                    float& s1, float& sT, float& st,
                                    float& A, float& Bv) {
    s1 += __expf(x);
    sT += __expf(x * 0.25f);
    float e = __expf(t * 0.25f);
    st += e;
    A  = fmaf(e, t, A);
    Bv = fmaf(e, x, Bv);
}

__global__ __launch_bounds__(256) void superloss_kernel(
    const float* __restrict__ logits,
    const float* __restrict__ teacher,
    const int*   __restrict__ targets,
    const float* __restrict__ ones,
    float* __restrict__ out)
{
    const int row = blockIdx.x;
    const size_t base_off = (size_t)row * NCLASS;
    const float4* lg = (const float4*)(logits  + base_off);
    const float4* tc = (const float4*)(teacher + base_off);

    float s1 = 0.f, sT = 0.f, st = 0.f, A = 0.f, Bv = 0.f;

    // 32000/4 = 8000 float4 pairs per row
    for (int j = threadIdx.x; j < NCLASS / 4; j += blockDim.x) {
        float4 xv = lg[j];
        float4 tv = tc[j];
        upd(xv.x, tv.x, s1, sT, st, A, Bv);
        upd(xv.y, tv.y, s1, sT, st, A, Bv);
        upd(xv.z, tv.z, s1, sT, st, A, Bv);
        upd(xv.w, tv.w, s1, sT, st, A, Bv);
    }

    // wave-64 shuffle reduction
#pragma unroll
    for (int off = 32; off > 0; off >>= 1) {
        s1 += __shfl_down(s1, off);
        sT += __shfl_down(sT, off);
        st += __shfl_down(st, off);
        A  += __shfl_down(A,  off);
        Bv += __shfl_down(Bv, off);
    }

    // cross-wave reduction (256 threads = 4 waves)
    __shared__ float red[4][5];
    const int wave = threadIdx.x >> 6;
    const int lane = threadIdx.x & 63;
    if (lane == 0) {
        red[wave][0] = s1; red[wave][1] = sT; red[wave][2] = st;
        red[wave][3] = A;  red[wave][4] = Bv;
    }
    __syncthreads();

    if (threadIdx.x == 0) {
        float fs1 = 0.f, fsT = 0.f, fst = 0.f, fA = 0.f, fB = 0.f;
#pragma unroll
        for (int w = 0; w < 4; ++w) {
            fs1 += red[w][0]; fsT += red[w][1]; fst += red[w][2];
            fA  += red[w][3]; fB  += red[w][4];
        }

        const float xt = logits[base_off + (size_t)targets[row]];
        const float o0 = ones[row * 2 + 0];
        const float o1 = ones[row * 2 + 1];

        double lse   = log((double)fs1);
        double lseT  = log((double)fsT);
        double lseTt = log((double)fst);

        double ce = lse - (double)xt;
        double kl = ((double)fA - (double)fB) / ((double)fst * (double)TEMP_F)
                    - lseTt + lseT;

        double base = (double)o0 * ce
                    + (double)(TEMP_F * TEMP_F) * (double)o1 * kl;

        double y = 0.5 * fmax(-2.0 / E_D, (base - TAU_D));  // LAM = 1
        double w = lambertw_d(y);
        double sigma = exp(-w);
        // LAM * log(sigma)^2 == w^2
        double loss = (base - TAU_D) * sigma + w * w;

        atomicAdd(out, (float)(loss / 2048.0));
    }
}

extern "C" void kernel_launch(void* const* d_in, const int* in_sizes, int n_in,
                              void* d_out, int out_size, void* d_ws, size_t ws_size,
                              hipStream_t stream) {
    const float* logits  = (const float*)d_in[0];
    const float* teacher = (const float*)d_in[1];
    const int*   targets = (const int*)d_in[2];
    const float* ones    = (const float*)d_in[3];
    float* out = (float*)d_out;

    // d_out is poisoned with 0xAA before every launch — zero it (capture-legal).
    hipMemsetAsync(out, 0, sizeof(float) * (size_t)out_size, stream);

    superloss_kernel<<<NROWS, 256, 0, stream>>>(logits, teacher, targets, ones, out);
}

// Round 2
// 502.289 us; speedup vs baseline: 1.0308x; 1.0308x over previous
//
#include <hip/hip_runtime.h>
#include <math.h>

#define NCLASS 32000
#define NROWS  2048
#define T1     320          // kernel1 threads = 5 waves; 8000/320 = 25 float4 per thread
#define U      5            // float4-pairs per pipeline stage
#define STAGES 5            // U*STAGES*T1 = 8000 float4 = 32000 floats

#define TAU_D 10.373491181781864
#define E_D   2.718281828459045

// Principal-branch Lambert W, mirrors the reference's 8 Halley iterations.
__device__ __forceinline__ double lambertw_d(double y) {
    double ey1 = fmax(E_D * y + 1.0, 0.0);
    double w_small = -1.0 + sqrt(2.0 * ey1);
    double ys = fmax(y, 1.0 + 1e-6);
    double ly = log(ys);
    double w_big = ly - log(fmax(ly, 1e-6));
    double w = (y < 1.0) ? w_small : w_big;
#pragma unroll
    for (int i = 0; i < 8; ++i) {
        double ew = exp(w);
        double f = w * ew - y;
        double wp1 = w + 1.0;
        double safe_wp1 = (fabs(wp1) > 1e-6) ? wp1 : 1e-6;
        double denom = ew * wp1 - (w + 2.0) * f / (2.0 * safe_wp1);
        if (!(fabs(denom) > 1e-12)) denom = 1e-12;
        w = w - f / denom;
    }
    return w;
}

// Per-element update: 2 transcendentals (exp(x) reconstructed as exp(x/4)^4).
__device__ __forceinline__ void upd(float x, float t,
                                    float& s1, float& sT, float& st,
                                    float& A, float& Bv) {
    float ex4 = __expf(x * 0.25f);
    float ex2 = ex4 * ex4;
    s1 += ex2 * ex2;        // e^x
    sT += ex4;              // e^{x/4}
    float et = __expf(t * 0.25f);
    st += et;               // e^{t/4}
    A  = fmaf(et, t, A);    // e^{t/4} * t
    Bv = fmaf(et, x, Bv);   // e^{t/4} * x
}

// Kernel 1: pure fp32 streaming reduction. One block per row, deep-pipelined
// loads (2 batches of 10 dwordx4 in flight -> progressive vmcnt waits).
__global__ __launch_bounds__(T1) void sums_kernel(
    const float* __restrict__ logits,
    const float* __restrict__ teacher,
    float* __restrict__ ws)          // [NROWS][5]
{
    const int row = blockIdx.x;
    const size_t base = (size_t)row * NCLASS;
    const float4* __restrict__ lg = (const float4*)(logits  + base);
    const float4* __restrict__ tc = (const float4*)(teacher + base);
    const int tid = threadIdx.x;

    float s1 = 0.f, sT = 0.f, st = 0.f, A = 0.f, Bv = 0.f;
    float4 xa[U], ta[U], xb[U], tb[U];

    auto load_stage = [&](float4* xd, float4* td, int s) {
#pragma unroll
        for (int k = 0; k < U; ++k) {
            const int j = tid + (s * U + k) * T1;
            xd[k] = lg[j];
            td[k] = tc[j];
        }
    };
    auto compute_stage = [&](const float4* xd, const float4* td) {
#pragma unroll
        for (int k = 0; k < U; ++k) {
            upd(xd[k].x, td[k].x, s1, sT, st, A, Bv);
            upd(xd[k].y, td[k].y, s1, sT, st, A, Bv);
            upd(xd[k].z, td[k].z, s1, sT, st, A, Bv);
            upd(xd[k].w, td[k].w, s1, sT, st, A, Bv);
        }
    };

    // software pipeline: always one batch in flight while computing the other
    load_stage(xa, ta, 0);
    load_stage(xb, tb, 1);
    compute_stage(xa, ta);
    load_stage(xa, ta, 2);
    compute_stage(xb, tb);
    load_stage(xb, tb, 3);
    compute_stage(xa, ta);
    load_stage(xa, ta, 4);
    compute_stage(xb, tb);
    compute_stage(xa, ta);

    // wave-64 shuffle reduction
#pragma unroll
    for (int off = 32; off > 0; off >>= 1) {
        s1 += __shfl_down(s1, off);
        sT += __shfl_down(sT, off);
        st += __shfl_down(st, off);
        A  += __shfl_down(A,  off);
        Bv += __shfl_down(Bv, off);
    }

    __shared__ float red[T1 / 64][5];
    const int wave = tid >> 6;
    const int lane = tid & 63;
    if (lane == 0) {
        red[wave][0] = s1; red[wave][1] = sT; red[wave][2] = st;
        red[wave][3] = A;  red[wave][4] = Bv;
    }
    __syncthreads();

    // threads 0..4 each finalize one partial
    if (tid < 5) {
        float acc = 0.f;
#pragma unroll
        for (int w = 0; w < T1 / 64; ++w) acc += red[w][tid];
        ws[row * 5 + tid] = acc;
    }
}

// Kernel 2: per-row scalar math (fp64) + global reduction. 8 blocks x 256,
// one row per thread.
__global__ __launch_bounds__(256) void finalize_kernel(
    const float* __restrict__ logits,
    const int*   __restrict__ targets,
    const float* __restrict__ ones,
    const float* __restrict__ ws,
    float* __restrict__ out)
{
    const int r = blockIdx.x * 256 + threadIdx.x;   // 8*256 == NROWS exactly

    const float fs1 = ws[r * 5 + 0];
    const float fsT = ws[r * 5 + 1];
    const float fst = ws[r * 5 + 2];
    const float fA  = ws[r * 5 + 3];
    const float fB  = ws[r * 5 + 4];

    const float xt = logits[(size_t)r * NCLASS + (size_t)targets[r]];
    const float o0 = ones[2 * r + 0];
    const float o1 = ones[2 * r + 1];

    const double lse   = log((double)fs1);
    const double lseT  = log((double)fsT);
    const double lseTt = log((double)fst);

    const double ce = lse - (double)xt;
    const double kl = ((double)fA - (double)fB) / ((double)fst * 4.0)
                      - lseTt + lseT;

    const double base = (double)o0 * ce + 16.0 * (double)o1 * kl;

    const double y = 0.5 * fmax(-2.0 / E_D, (base - TAU_D));   // LAM = 1
    const double w = lambertw_d(y);
    const double sigma = exp(-w);
    double loss = (base - TAU_D) * sigma + w * w;               // log(sigma)^2 = w^2

    // block reduction (4 waves of 64)
#pragma unroll
    for (int off = 32; off > 0; off >>= 1)
        loss += __shfl_down(loss, off);

    __shared__ double red2[4];
    const int wave = threadIdx.x >> 6;
    const int lane = threadIdx.x & 63;
    if (lane == 0) red2[wave] = loss;
    __syncthreads();

    if (threadIdx.x == 0) {
        double acc = red2[0] + red2[1] + red2[2] + red2[3];
        atomicAdd(out, (float)(acc / 2048.0));
    }
}

extern "C" void kernel_launch(void* const* d_in, const int* in_sizes, int n_in,
                              void* d_out, int out_size, void* d_ws, size_t ws_size,
                              hipStream_t stream) {
    const float* logits  = (const float*)d_in[0];
    const float* teacher = (const float*)d_in[1];
    const int*   targets = (const int*)d_in[2];
    const float* ones    = (const float*)d_in[3];
    float* out = (float*)d_out;
    float* ws  = (float*)d_ws;

    hipMemsetAsync(out, 0, sizeof(float) * (size_t)out_size, stream);

    sums_kernel<<<NROWS, T1, 0, stream>>>(logits, teacher, ws);
    finalize_kernel<<<NROWS / 256, 256, 0, stream>>>(logits, targets, ones, ws, out);
}